// Round 10
// baseline (351.549 us; speedup 1.0000x reference)
//
#include <hip/hip_runtime.h>
#include <hip/hip_bf16.h>

#define HIDDEN 1024
#define INTER 2048
#define NE 8
#define GS 128
#define TOKENS 4096
#define MAXROWS 9216  // 8192 routed rows + 8*128 padding capacity
#define MAXTILES 72

typedef __bf16 bf16x8 __attribute__((ext_vector_type(8)));
typedef float f32x4 __attribute__((ext_vector_type(4)));

// ---- ws layout (bytes) ----
#define OFF_TOPKI 0u               // int[4096][2]
#define OFF_TOPKW 32768u           // float[4096][2]
#define OFF_CTRL  65536u           // int[32]
#define OFF_TOK   66048u           // int[MAXROWS]
#define OFF_SLOT  102912u          // int[TOKENS*2]
#define OFF_TILE  135680u          // int[MAXTILES]
#define OFF_XB    139776u          // bf16[TOKENS+1][HIDDEN]  (row TOKENS = zeros)
#define OFF_A     8530432u         // a_f: bf16 frag-order [576 rt][64 kt][64 lane][8]
#define OFF_W1D   46279168u        // w1f: bf16 frag-order [8 e][256 ntP][32 kt][64 lane][8] (dead after gemm1)
#define OFF_W2D   113388032u       // w2f: bf16 frag-order [8 e][64 ntP][64 kt][64 lane][8]  -> 146942464 total
#define OFF_Y0    OFF_W1D          // y: bf16[2][MAXROWS][HIDDEN] (aliases dead w1f)

__device__ __forceinline__ unsigned short f2bf(float f) {
  union { float f; unsigned int u; } v; v.f = f;
  unsigned int r = (v.u + 0x7FFFu + ((v.u >> 16) & 1u)) >> 16;
  return (unsigned short)r;
}
__device__ __forceinline__ float bf2f(unsigned int u) {
  union { unsigned int u; float f; } v; v.u = u << 16;
  return v.f;
}
__device__ __forceinline__ unsigned int pack2(unsigned short lo, unsigned short hi) {
  return (unsigned int)lo | ((unsigned int)hi << 16);
}

typedef const __attribute__((address_space(1))) unsigned int GAS;
typedef __attribute__((address_space(3))) unsigned int LAS;
__device__ __forceinline__ void gload16(const unsigned short* g, unsigned short* l) {
  __builtin_amdgcn_global_load_lds((GAS*)g, (LAS*)l, 16, 0, 0);
}

// Fragment-order convention (matches verified MFMA operand layouts):
//   frag(tile16, kt32, lane, j) holds M[tile16*16 + (lane&15)][kt*32 + (lane>>4)*8 + j]
// A wave's operand load = base + lane*16B  -> one coalesced global_load_dwordx4.

// ---- prep: router+xconv | deq1->w1f | deq2->w2f | zero-row -----------------
__global__ __launch_bounds__(256) void k_prep(const float* __restrict__ x,
    const float* __restrict__ rw, int* __restrict__ topki, float* __restrict__ topkw,
    const int* __restrict__ w1, const float* __restrict__ w1s,
    unsigned short* __restrict__ w1f,
    const int* __restrict__ w2, const float* __restrict__ w2s,
    unsigned short* __restrict__ w2f, unsigned short* __restrict__ xb) {
  int bid = blockIdx.x, tid = threadIdx.x;
  if (bid == 25600) {
    uint2 z; z.x = 0u; z.y = 0u;
    *reinterpret_cast<uint2*>(xb + (size_t)TOKENS * HIDDEN + tid * 4) = z;
    return;
  }
  if (bid >= 17408) {
    // ---- deq2 -> w2f fragment order ----
    int gid = (bid - 17408) * 256 + tid;
    int lane = gid & 63, kt = (gid >> 6) & 63, ntP = (gid >> 12) & 63, e = gid >> 18;
    int n = ntP * 16 + (lane & 15), q = lane >> 4;
    size_t R = (size_t)e * 1024 + n;
    float s = w2s[R * 16 + (kt >> 2)];
    int4 p = *reinterpret_cast<const int4*>(w2 + R * 1024 + kt * 16 + q * 4);
    int pv[4] = { p.x, p.y, p.z, p.w };
    uint4 o; unsigned int ov[4];
#pragma unroll
    for (int j = 0; j < 4; j++) {
      float lo = (float)((pv[j] & 15) - 8) * s;
      float hi = (float)(((pv[j] >> 4) & 15) - 8) * s;
      ov[j] = pack2(f2bf(lo), f2bf(hi));
    }
    o.x = ov[0]; o.y = ov[1]; o.z = ov[2]; o.w = ov[3];
    *reinterpret_cast<uint4*>(w2f + (size_t)gid * 8) = o;
    return;
  }
  if (bid >= 1024) {
    // ---- deq1 -> w1f fragment order ----
    int gid = (bid - 1024) * 256 + tid;
    int lane = gid & 63, kt = (gid >> 6) & 31, ntP = (gid >> 11) & 255, e = gid >> 19;
    int n = ntP * 16 + (lane & 15), q = lane >> 4;
    size_t R = (size_t)e * 4096 + n;
    float s = w1s[R * 8 + (kt >> 2)];
    int4 p = *reinterpret_cast<const int4*>(w1 + R * 512 + kt * 16 + q * 4);
    int pv[4] = { p.x, p.y, p.z, p.w };
    uint4 o; unsigned int ov[4];
#pragma unroll
    for (int j = 0; j < 4; j++) {
      float lo = (float)((pv[j] & 15) - 8) * s;
      float hi = (float)(((pv[j] >> 4) & 15) - 8) * s;
      ov[j] = pack2(f2bf(lo), f2bf(hi));
    }
    o.x = ov[0]; o.y = ov[1]; o.z = ov[2]; o.w = ov[3];
    *reinterpret_cast<uint4*>(w1f + (size_t)gid * 8) = o;
    return;
  }
  // ---- router + xconv ----
  int wave = tid >> 6, lane = tid & 63;
  int t = bid * 4 + wave;
  float acc[NE];
#pragma unroll
  for (int e = 0; e < NE; e++) acc[e] = 0.f;
  const float* xr = x + (size_t)t * HIDDEN;
  unsigned short* xbr = xb + (size_t)t * HIDDEN;
  for (int i = lane; i < HIDDEN; i += 64) {
    float xv = xr[i];
    xbr[i] = f2bf(xv);
#pragma unroll
    for (int e = 0; e < NE; e++) acc[e] += xv * rw[e * HIDDEN + i];
  }
#pragma unroll
  for (int e = 0; e < NE; e++) {
    float v = acc[e];
    for (int off = 32; off > 0; off >>= 1) v += __shfl_down(v, off, 64);
    acc[e] = v;
  }
  if (lane == 0) {
    int b0 = 0; float s0 = acc[0];
#pragma unroll
    for (int e = 1; e < NE; e++) if (acc[e] > s0) { s0 = acc[e]; b0 = e; }
    int b1 = -1; float s1 = -3.0e38f;
#pragma unroll
    for (int e = 0; e < NE; e++) if (e != b0 && acc[e] > s1) { s1 = acc[e]; b1 = e; }
    float w0 = 1.f / (1.f + __expf(s1 - s0));
    topki[t * 2] = b0; topki[t * 2 + 1] = b1;
    topkw[t * 2] = w0; topkw[t * 2 + 1] = 1.f - w0;
  }
}

// ------- route2 (1 block): hist + offsets + tilemap + pad fill + scatter ----
__global__ __launch_bounds__(256) void k_route2(const int* __restrict__ topki,
    int* __restrict__ ctrl, int* __restrict__ tok, int* __restrict__ slots,
    int* __restrict__ tilemap) {
  __shared__ int h[NE], off[NE], cnt[NE];
  int tid = threadIdx.x;
  if (tid < NE) h[tid] = 0;
  __syncthreads();
  for (int i = tid; i < TOKENS * 2; i += 256) atomicAdd(&h[topki[i]], 1);
  __syncthreads();
  if (tid == 0) {
    int run = 0, t = 0;
    for (int e = 0; e < NE; e++) {
      int c = h[e];
      ctrl[e] = c; ctrl[16 + e] = run; off[e] = run;
      int pc = (c + 127) & ~127;
      for (int mt = 0; mt < (pc >> 7); mt++) tilemap[t++] = (e << 20) | (run + mt * 128);
      run += pc;
    }
    ctrl[24] = run; ctrl[25] = t;
  }
  __syncthreads();
#pragma unroll
  for (int e = 0; e < NE; e++) {
    int c = h[e], pc = (c + 127) & ~127;
    for (int i = c + tid; i < pc; i += 256) tok[off[e] + i] = -1;
  }
  if (tid < NE) cnt[tid] = off[tid];
  __syncthreads();
  for (int i = tid; i < TOKENS * 2; i += 256) {
    int e = topki[i];
    int p = atomicAdd(&cnt[e], 1);
    tok[p] = i >> 1;
    slots[i] = p;
  }
}

// --------------- GEMM1: A via LDS (gather), B direct from w1f ---------------
// 128 rows x (64 gate + 64 up), BK=32. Epilogue writes a in gemm2-A-frag order.
__global__ __launch_bounds__(256) void k_gemm1(
    const unsigned short* __restrict__ xb, const unsigned short* __restrict__ w1f,
    const int* __restrict__ ctrl, const int* __restrict__ tilemap,
    const int* __restrict__ tok, unsigned short* __restrict__ a_f) {
  __shared__ unsigned short sA[128 * 32];   // 8 KB (A only)
  int bid = blockIdx.x, tid = threadIdx.x;
  int nt = bid & 31, tile = bid >> 5;
  if (tile >= ctrl[25]) return;
  int tm = tilemap[tile];
  int e = tm >> 20, row0 = tm & 0xFFFFF;
  int wave = tid >> 6, lane = tid & 63;
  int ln = lane & 15, quad = lane >> 4;
  int wr = (wave & 1) * 64, wc = (wave >> 1) * 32;

  // A staging (swizzled, proven conflict-free)
  int srow = tid >> 2, scblk = tid & 3;
  int scol = (scblk ^ ((srow >> 1) & 3)) * 8;
  int t0 = tok[row0 + srow];
  int t1 = tok[row0 + 64 + srow];
  const unsigned short* gA0 = xb + (size_t)(t0 < 0 ? TOKENS : t0) * HIDDEN + scol;
  const unsigned short* gA1 = xb + (size_t)(t1 < 0 ? TOKENS : t1) * HIDDEN + scol;
  unsigned short* lA0 = sA + tid * 8;
  unsigned short* lA1 = sA + 64 * 32 + tid * 8;

  // B fragment pointers (ntP: gate = nt*4 + (wave>>1)*2 + n, up = +128)
  int ntPg = nt * 4 + (wave >> 1) * 2;
  const unsigned short* pbg0 = w1f + (size_t)(e * 256 + ntPg) * 16384 + lane * 8;
  const unsigned short* pbg1 = w1f + (size_t)(e * 256 + ntPg + 1) * 16384 + lane * 8;
  const unsigned short* pbu0 = w1f + (size_t)(e * 256 + 128 + ntPg) * 16384 + lane * 8;
  const unsigned short* pbu1 = w1f + (size_t)(e * 256 + 128 + ntPg + 1) * 16384 + lane * 8;

  bf16x8 bgc[2], buc[2];
  bgc[0] = *reinterpret_cast<const bf16x8*>(pbg0);
  bgc[1] = *reinterpret_cast<const bf16x8*>(pbg1);
  buc[0] = *reinterpret_cast<const bf16x8*>(pbu0);
  buc[1] = *reinterpret_cast<const bf16x8*>(pbu1);

  f32x4 aG[4][2] = {}, aU[4][2] = {};
#pragma unroll 2
  for (int kt = 0; kt < 32; kt++) {
    __syncthreads();
    gload16(gA0 + kt * 32, lA0);
    gload16(gA1 + kt * 32, lA1);
    __syncthreads();
    int o = (kt < 31) ? (kt + 1) * 512 : 0;   // prefetch next B (guarded)
    bf16x8 bgn0 = *reinterpret_cast<const bf16x8*>(pbg0 + o);
    bf16x8 bgn1 = *reinterpret_cast<const bf16x8*>(pbg1 + o);
    bf16x8 bun0 = *reinterpret_cast<const bf16x8*>(pbu0 + o);
    bf16x8 bun1 = *reinterpret_cast<const bf16x8*>(pbu1 + o);
    bf16x8 af[4];
#pragma unroll
    for (int m = 0; m < 4; m++) {
      int ar = wr + m * 16 + ln;
      af[m] = *reinterpret_cast<const bf16x8*>(&sA[ar * 32 + (quad ^ ((ar >> 1) & 3)) * 8]);
    }
#pragma unroll
    for (int m = 0; m < 4; m++) {
      aG[m][0] = __builtin_amdgcn_mfma_f32_16x16x32_bf16(af[m], bgc[0], aG[m][0], 0, 0, 0);
      aG[m][1] = __builtin_amdgcn_mfma_f32_16x16x32_bf16(af[m], bgc[1], aG[m][1], 0, 0, 0);
      aU[m][0] = __builtin_amdgcn_mfma_f32_16x16x32_bf16(af[m], buc[0], aU[m][0], 0, 0, 0);
      aU[m][1] = __builtin_amdgcn_mfma_f32_16x16x32_bf16(af[m], buc[1], aU[m][1], 0, 0, 0);
    }
    bgc[0] = bgn0; bgc[1] = bgn1; buc[0] = bun0; buc[1] = bun1;
  }
  // epilogue: silu(g)*u -> a_f in gemm2-A-fragment order
#pragma unroll
  for (int m = 0; m < 4; m++)
#pragma unroll
    for (int n = 0; n < 2; n++) {
      int c = nt * 64 + wc + n * 16 + ln;          // a col in [0,2048)
      int kta = c >> 5, qa = (c >> 3) & 3, ja = c & 7;
#pragma unroll
      for (int r = 0; r < 4; r++) {
        float g = aG[m][n][r], u = aU[m][n][r];
        float act = (g / (1.f + __expf(-g))) * u;
        int row = row0 + wr + m * 16 + quad * 4 + r;
        size_t idx = ((size_t)((row >> 4) * 64 + kta) * 64 + qa * 16 + (row & 15)) * 8 + ja;
        a_f[idx] = f2bf(act);
      }
    }
}

// ------- GEMM2 split-K x2: no LDS, no barriers; A from a_f, B from w2f -----
__global__ __launch_bounds__(256) void k_gemm2(
    const unsigned short* __restrict__ a_f, const unsigned short* __restrict__ w2f,
    const int* __restrict__ ctrl, const int* __restrict__ tilemap,
    unsigned short* __restrict__ y) {
  int bid = blockIdx.x, tid = threadIdx.x;
  int kp = bid & 1, nt = (bid >> 1) & 7, tile = bid >> 4;
  if (tile >= ctrl[25]) return;
  int tm = tilemap[tile];
  int e = tm >> 20, row0 = tm & 0xFFFFF;
  int n0 = nt * 128;
  int wave = tid >> 6, lane = tid & 63;
  int ln = lane & 15, quad = lane >> 4;
  int wr = (wave & 1) * 64, wc = (wave >> 1) * 64;

  int rt0 = (row0 >> 4) + (wave & 1) * 4;
  int ntP0 = nt * 8 + (wave >> 1) * 4;
  const unsigned short* pa[4];
  const unsigned short* pb[4];
#pragma unroll
  for (int m = 0; m < 4; m++)
    pa[m] = a_f + ((size_t)(rt0 + m) * 64 + kp * 32) * 512 + lane * 8;
#pragma unroll
  for (int n = 0; n < 4; n++)
    pb[n] = w2f + ((size_t)(e * 64 + ntP0 + n) * 64 + kp * 32) * 512 + lane * 8;

  bf16x8 ac[4], bc[4];
#pragma unroll
  for (int m = 0; m < 4; m++) ac[m] = *reinterpret_cast<const bf16x8*>(pa[m]);
#pragma unroll
  for (int n = 0; n < 4; n++) bc[n] = *reinterpret_cast<const bf16x8*>(pb[n]);

  f32x4 acc[4][4] = {};
#pragma unroll 2
  for (int i = 0; i < 32; i++) {
    int o = (i < 31) ? (i + 1) * 512 : 0;   // prefetch next (guarded vs ws end)
    bf16x8 an[4], bn[4];
#pragma unroll
    for (int m = 0; m < 4; m++) an[m] = *reinterpret_cast<const bf16x8*>(pa[m] + o);
#pragma unroll
    for (int n = 0; n < 4; n++) bn[n] = *reinterpret_cast<const bf16x8*>(pb[n] + o);
#pragma unroll
    for (int m = 0; m < 4; m++)
#pragma unroll
      for (int n = 0; n < 4; n++)
        acc[m][n] = __builtin_amdgcn_mfma_f32_16x16x32_bf16(ac[m], bc[n], acc[m][n], 0, 0, 0);
#pragma unroll
    for (int m = 0; m < 4; m++) ac[m] = an[m];
#pragma unroll
    for (int n = 0; n < 4; n++) bc[n] = bn[n];
  }
  unsigned short* yk = y + (size_t)kp * MAXROWS * HIDDEN;
#pragma unroll
  for (int m = 0; m < 4; m++)
#pragma unroll
    for (int n = 0; n < 4; n++) {
      int col = n0 + wc + n * 16 + ln;
#pragma unroll
      for (int r = 0; r < 4; r++) {
        int row = row0 + wr + m * 16 + quad * 4 + r;
        yk[(size_t)row * HIDDEN + col] = f2bf(acc[m][n][r]);
      }
    }
}

// ------- combine: out[t] = g0*(y0[s0]+y1[s0]) + g1*(y0[s1]+y1[s1]) ---------
__global__ __launch_bounds__(256) void k_combine(const unsigned short* __restrict__ y,
    const int* __restrict__ slots, const float* __restrict__ topkw,
    float* __restrict__ out) {
  int t = blockIdx.x;
  int c = threadIdx.x * 4;
  int s0 = slots[t * 2], s1 = slots[t * 2 + 1];
  float g0 = topkw[t * 2], g1 = topkw[t * 2 + 1];
  const unsigned short* y1 = y + (size_t)MAXROWS * HIDDEN;
  uint2 a0 = *reinterpret_cast<const uint2*>(y  + (size_t)s0 * HIDDEN + c);
  uint2 a1 = *reinterpret_cast<const uint2*>(y1 + (size_t)s0 * HIDDEN + c);
  uint2 b0 = *reinterpret_cast<const uint2*>(y  + (size_t)s1 * HIDDEN + c);
  uint2 b1 = *reinterpret_cast<const uint2*>(y1 + (size_t)s1 * HIDDEN + c);
  float4 o;
  o.x = g0 * (bf2f(a0.x & 0xffffu) + bf2f(a1.x & 0xffffu))
      + g1 * (bf2f(b0.x & 0xffffu) + bf2f(b1.x & 0xffffu));
  o.y = g0 * (bf2f(a0.x >> 16) + bf2f(a1.x >> 16))
      + g1 * (bf2f(b0.x >> 16) + bf2f(b1.x >> 16));
  o.z = g0 * (bf2f(a0.y & 0xffffu) + bf2f(a1.y & 0xffffu))
      + g1 * (bf2f(b0.y & 0xffffu) + bf2f(b1.y & 0xffffu));
  o.w = g0 * (bf2f(a0.y >> 16) + bf2f(a1.y >> 16))
      + g1 * (bf2f(b0.y >> 16) + bf2f(b1.y >> 16));
  *reinterpret_cast<float4*>(out + (size_t)t * HIDDEN + c) = o;
}

extern "C" void kernel_launch(void* const* d_in, const int* in_sizes, int n_in,
                              void* d_out, int out_size, void* d_ws, size_t ws_size,
                              hipStream_t stream) {
  const float* x   = (const float*)d_in[0];
  const float* rw  = (const float*)d_in[1];
  const int*   w1  = (const int*)d_in[2];
  const float* w1s = (const float*)d_in[3];
  const int*   w2  = (const int*)d_in[4];
  const float* w2s = (const float*)d_in[5];
  float* out = (float*)d_out;
  char* ws = (char*)d_ws;

  int*   topki = (int*)(ws + OFF_TOPKI);
  float* topkw = (float*)(ws + OFF_TOPKW);
  int*   ctrl  = (int*)(ws + OFF_CTRL);
  int*   tok   = (int*)(ws + OFF_TOK);
  int*   slots = (int*)(ws + OFF_SLOT);
  int*   tilemap = (int*)(ws + OFF_TILE);
  unsigned short* xb  = (unsigned short*)(ws + OFF_XB);
  unsigned short* a_f = (unsigned short*)(ws + OFF_A);
  unsigned short* w1f = (unsigned short*)(ws + OFF_W1D);
  unsigned short* w2f = (unsigned short*)(ws + OFF_W2D);
  unsigned short* y   = (unsigned short*)(ws + OFF_Y0);  // aliases dead w1f

  k_prep<<<25601, 256, 0, stream>>>(x, rw, topki, topkw, w1, w1s, w1f, w2, w2s, w2f, xb);
  k_route2<<<1, 256, 0, stream>>>(topki, ctrl, tok, slots, tilemap);
  k_gemm1<<<32 * MAXTILES, 256, 0, stream>>>(xb, w1f, ctrl, tilemap, tok, a_f);
  k_gemm2<<<16 * MAXTILES, 256, 0, stream>>>(a_f, w2f, ctrl, tilemap, y);
  k_combine<<<TOKENS, 256, 0, stream>>>(y, slots, topkw, out);
}

// Round 11
// 328.531 us; speedup vs baseline: 1.0701x; 1.0701x over previous
//
#include <hip/hip_runtime.h>
#include <hip/hip_bf16.h>

#define HIDDEN 1024
#define INTER 2048
#define NE 8
#define GS 128
#define TOKENS 4096
#define MAXROWS 9216  // 8192 routed rows + 8*128 padding capacity
#define MAXTILES 72

typedef __bf16 bf16x8 __attribute__((ext_vector_type(8)));
typedef float f32x4 __attribute__((ext_vector_type(4)));

// ---- ws layout (bytes) ----
#define OFF_TOPKI 0u               // int[4096][2]
#define OFF_TOPKW 32768u           // float[4096][2]
#define OFF_CTRL  65536u           // int[32]
#define OFF_TOK   66048u           // int[MAXROWS]
#define OFF_SLOT  102912u          // int[TOKENS*2]
#define OFF_TILE  135680u          // int[MAXTILES]
#define OFF_XB    139776u          // bf16[TOKENS+1][HIDDEN]  (row TOKENS = zeros)
#define OFF_A     8530432u         // a_f: bf16 frag-order [576 rt][64 kt][64 lane][8]
#define OFF_W1D   46279168u        // w1d: bf16 row-major [8 e][4096][1024] (dead after gemm1)
#define OFF_W2D   113388032u       // w2f: bf16 frag-order [8 e][64 ntP][64 kt][64 lane][8] -> 146942464
#define OFF_Y0    OFF_W1D          // y: bf16[2][MAXROWS][HIDDEN] (aliases dead w1d)

__device__ __forceinline__ unsigned short f2bf(float f) {
  union { float f; unsigned int u; } v; v.f = f;
  unsigned int r = (v.u + 0x7FFFu + ((v.u >> 16) & 1u)) >> 16;
  return (unsigned short)r;
}
__device__ __forceinline__ float bf2f(unsigned int u) {
  union { unsigned int u; float f; } v; v.u = u << 16;
  return v.f;
}
__device__ __forceinline__ unsigned int pack2(unsigned short lo, unsigned short hi) {
  return (unsigned int)lo | ((unsigned int)hi << 16);
}

typedef const __attribute__((address_space(1))) unsigned int GAS;
typedef __attribute__((address_space(3))) unsigned int LAS;
__device__ __forceinline__ void gload16(const unsigned short* g, unsigned short* l) {
  __builtin_amdgcn_global_load_lds((GAS*)g, (LAS*)l, 16, 0, 0);
}

// XOR swizzle (BK=32): LDS slot (row, cblk) holds global (row, cblk^((row>>1)&3)).
// Measured 0 bank conflicts (R4/R6/R7/R9).
// Fragment-order convention (verified end-to-end in R10, absmax 2.0):
//   frag(tile16, kt32, lane, j) holds M[tile16*16 + (lane&15)][kt*32 + (lane>>4)*8 + j]

// ---- prep: router+xconv | deq1->w1d(row-major) | deq2->w2f(frag) | zeros ---
__global__ __launch_bounds__(256) void k_prep(const float* __restrict__ x,
    const float* __restrict__ rw, int* __restrict__ topki, float* __restrict__ topkw,
    const int* __restrict__ w1, const float* __restrict__ w1s,
    unsigned short* __restrict__ w1d,
    const int* __restrict__ w2, const float* __restrict__ w2s,
    unsigned short* __restrict__ w2f, unsigned short* __restrict__ xb) {
  int bid = blockIdx.x, tid = threadIdx.x;
  if (bid == 25600) {
    uint2 z; z.x = 0u; z.y = 0u;
    *reinterpret_cast<uint2*>(xb + (size_t)TOKENS * HIDDEN + tid * 4) = z;
    return;
  }
  if (bid >= 17408) {
    // ---- deq2 -> w2f fragment order (verified R10) ----
    int gid = (bid - 17408) * 256 + tid;
    int lane = gid & 63, kt = (gid >> 6) & 63, ntP = (gid >> 12) & 63, e = gid >> 18;
    int n = ntP * 16 + (lane & 15), q = lane >> 4;
    size_t R = (size_t)e * 1024 + n;
    float s = w2s[R * 16 + (kt >> 2)];
    int4 p = *reinterpret_cast<const int4*>(w2 + R * 1024 + kt * 16 + q * 4);
    int pv[4] = { p.x, p.y, p.z, p.w };
    uint4 o; unsigned int ov[4];
#pragma unroll
    for (int j = 0; j < 4; j++) {
      float lo = (float)((pv[j] & 15) - 8) * s;
      float hi = (float)(((pv[j] >> 4) & 15) - 8) * s;
      ov[j] = pack2(f2bf(lo), f2bf(hi));
    }
    o.x = ov[0]; o.y = ov[1]; o.z = ov[2]; o.w = ov[3];
    *reinterpret_cast<uint4*>(w2f + (size_t)gid * 8) = o;
    return;
  }
  if (bid >= 1024) {
    // ---- deq1 -> w1d row-major (R9-proven, feeds LDS-staged B) ----
    int gid = (bid - 1024) * 256 + tid;
    int i4 = gid * 4;
    int r = i4 >> 9;
    int i = i4 & 511;
    float s = w1s[r * 8 + (i >> 6)];
    int4 p = *reinterpret_cast<const int4*>(w1 + (size_t)i4);
    int pv[4] = { p.x, p.y, p.z, p.w };
    uint4 o; unsigned int ov[4];
#pragma unroll
    for (int j = 0; j < 4; j++) {
      float lo = (float)((pv[j] & 15) - 8) * s;
      float hi = (float)(((pv[j] >> 4) & 15) - 8) * s;
      ov[j] = pack2(f2bf(lo), f2bf(hi));
    }
    o.x = ov[0]; o.y = ov[1]; o.z = ov[2]; o.w = ov[3];
    *reinterpret_cast<uint4*>(w1d + ((size_t)r << 10) + 2 * i) = o;
    return;
  }
  // ---- router + xconv ----
  int wave = tid >> 6, lane = tid & 63;
  int t = bid * 4 + wave;
  float acc[NE];
#pragma unroll
  for (int e = 0; e < NE; e++) acc[e] = 0.f;
  const float* xr = x + (size_t)t * HIDDEN;
  unsigned short* xbr = xb + (size_t)t * HIDDEN;
  for (int i = lane; i < HIDDEN; i += 64) {
    float xv = xr[i];
    xbr[i] = f2bf(xv);
#pragma unroll
    for (int e = 0; e < NE; e++) acc[e] += xv * rw[e * HIDDEN + i];
  }
#pragma unroll
  for (int e = 0; e < NE; e++) {
    float v = acc[e];
    for (int off = 32; off > 0; off >>= 1) v += __shfl_down(v, off, 64);
    acc[e] = v;
  }
  if (lane == 0) {
    int b0 = 0; float s0 = acc[0];
#pragma unroll
    for (int e = 1; e < NE; e++) if (acc[e] > s0) { s0 = acc[e]; b0 = e; }
    int b1 = -1; float s1 = -3.0e38f;
#pragma unroll
    for (int e = 0; e < NE; e++) if (e != b0 && acc[e] > s1) { s1 = acc[e]; b1 = e; }
    float w0 = 1.f / (1.f + __expf(s1 - s0));
    topki[t * 2] = b0; topki[t * 2 + 1] = b1;
    topkw[t * 2] = w0; topkw[t * 2 + 1] = 1.f - w0;
  }
}

// ------- route2 (1 block): hist + offsets + tilemap + pad fill + scatter ----
__global__ __launch_bounds__(256) void k_route2(const int* __restrict__ topki,
    int* __restrict__ ctrl, int* __restrict__ tok, int* __restrict__ slots,
    int* __restrict__ tilemap) {
  __shared__ int h[NE], off[NE], cnt[NE];
  int tid = threadIdx.x;
  if (tid < NE) h[tid] = 0;
  __syncthreads();
  for (int i = tid; i < TOKENS * 2; i += 256) atomicAdd(&h[topki[i]], 1);
  __syncthreads();
  if (tid == 0) {
    int run = 0, t = 0;
    for (int e = 0; e < NE; e++) {
      int c = h[e];
      ctrl[e] = c; ctrl[16 + e] = run; off[e] = run;
      int pc = (c + 127) & ~127;
      for (int mt = 0; mt < (pc >> 7); mt++) tilemap[t++] = (e << 20) | (run + mt * 128);
      run += pc;
    }
    ctrl[24] = run; ctrl[25] = t;
  }
  __syncthreads();
#pragma unroll
  for (int e = 0; e < NE; e++) {
    int c = h[e], pc = (c + 127) & ~127;
    for (int i = c + tid; i < pc; i += 256) tok[off[e] + i] = -1;
  }
  if (tid < NE) cnt[tid] = off[tid];
  __syncthreads();
  for (int i = tid; i < TOKENS * 2; i += 256) {
    int e = topki[i];
    int p = atomicAdd(&cnt[e], 1);
    tok[p] = i >> 1;
    slots[i] = p;
  }
}

// --------------- GEMM1 (R9-proven): A+B via LDS; frag-order epilogue -------
// 128 rows x (64 gate + 64 up), BK=32, swizzled LDS, async staging.
__global__ __launch_bounds__(256) void k_gemm1(
    const unsigned short* __restrict__ xb, const unsigned short* __restrict__ w1d,
    const int* __restrict__ ctrl, const int* __restrict__ tilemap,
    const int* __restrict__ tok, unsigned short* __restrict__ a_f) {
  __shared__ unsigned short sA[128 * 32];   // 8 KB
  __shared__ unsigned short sBg[64 * 32];   // 4 KB
  __shared__ unsigned short sBu[64 * 32];   // 4 KB
  int bid = blockIdx.x, tid = threadIdx.x;
  int nt = bid & 31, tile = bid >> 5;
  if (tile >= ctrl[25]) return;
  int tm = tilemap[tile];
  int e = tm >> 20, row0 = tm & 0xFFFFF;
  int n0 = nt * 64;
  int wave = tid >> 6, lane = tid & 63;
  int ln = lane & 15, quad = lane >> 4;
  int wr = (wave & 1) * 64, wc = (wave >> 1) * 32;

  int srow = tid >> 2, scblk = tid & 3;
  int scol = (scblk ^ ((srow >> 1) & 3)) * 8;
  int t0 = tok[row0 + srow];
  int t1 = tok[row0 + 64 + srow];
  const unsigned short* gA0 = xb + (size_t)(t0 < 0 ? TOKENS : t0) * HIDDEN + scol;
  const unsigned short* gA1 = xb + (size_t)(t1 < 0 ? TOKENS : t1) * HIDDEN + scol;
  const unsigned short* gBg = w1d + ((size_t)e * 4096 + n0 + srow) * HIDDEN + scol;
  const unsigned short* gBu = gBg + (size_t)INTER * HIDDEN;
  unsigned short* lA0 = sA + tid * 8;
  unsigned short* lA1 = sA + 64 * 32 + tid * 8;
  unsigned short* lBg = sBg + tid * 8;
  unsigned short* lBu = sBu + tid * 8;

  f32x4 aG[4][2] = {}, aU[4][2] = {};
  for (int k0 = 0; k0 < HIDDEN; k0 += 32) {
    __syncthreads();
    gload16(gA0 + k0, lA0);
    gload16(gA1 + k0, lA1);
    gload16(gBg + k0, lBg);
    gload16(gBu + k0, lBu);
    __syncthreads();
    bf16x8 af[4], bg[2], bu[2];
#pragma unroll
    for (int m = 0; m < 4; m++) {
      int ar = wr + m * 16 + ln;
      af[m] = *reinterpret_cast<const bf16x8*>(&sA[ar * 32 + (quad ^ ((ar >> 1) & 3)) * 8]);
    }
#pragma unroll
    for (int n = 0; n < 2; n++) {
      int br = wc + n * 16 + ln;
      int bo = br * 32 + (quad ^ ((br >> 1) & 3)) * 8;
      bg[n] = *reinterpret_cast<const bf16x8*>(&sBg[bo]);
      bu[n] = *reinterpret_cast<const bf16x8*>(&sBu[bo]);
    }
#pragma unroll
    for (int m = 0; m < 4; m++)
#pragma unroll
      for (int n = 0; n < 2; n++) {
        aG[m][n] = __builtin_amdgcn_mfma_f32_16x16x32_bf16(af[m], bg[n], aG[m][n], 0, 0, 0);
        aU[m][n] = __builtin_amdgcn_mfma_f32_16x16x32_bf16(af[m], bu[n], aU[m][n], 0, 0, 0);
      }
  }
  // epilogue: silu(g)*u -> a_f in gemm2-A-fragment order (verified R10)
#pragma unroll
  for (int m = 0; m < 4; m++)
#pragma unroll
    for (int n = 0; n < 2; n++) {
      int c = n0 + wc + n * 16 + ln;              // a col in [0,2048)
      int kta = c >> 5, qa = (c >> 3) & 3, ja = c & 7;
#pragma unroll
      for (int r = 0; r < 4; r++) {
        float g = aG[m][n][r], u = aU[m][n][r];
        float act = (g / (1.f + __expf(-g))) * u;
        int row = row0 + wr + m * 16 + quad * 4 + r;
        size_t idx = ((size_t)((row >> 4) * 64 + kta) * 64 + qa * 16 + (row & 15)) * 8 + ja;
        a_f[idx] = f2bf(act);
      }
    }
}

// ------- GEMM2 (R10-verified): split-K x2, no LDS, no barriers -------------
__global__ __launch_bounds__(256) void k_gemm2(
    const unsigned short* __restrict__ a_f, const unsigned short* __restrict__ w2f,
    const int* __restrict__ ctrl, const int* __restrict__ tilemap,
    unsigned short* __restrict__ y) {
  int bid = blockIdx.x, tid = threadIdx.x;
  int kp = bid & 1, nt = (bid >> 1) & 7, tile = bid >> 4;
  if (tile >= ctrl[25]) return;
  int tm = tilemap[tile];
  int e = tm >> 20, row0 = tm & 0xFFFFF;
  int n0 = nt * 128;
  int wave = tid >> 6, lane = tid & 63;
  int ln = lane & 15, quad = lane >> 4;
  int wr = (wave & 1) * 64, wc = (wave >> 1) * 64;

  int rt0 = (row0 >> 4) + (wave & 1) * 4;
  int ntP0 = nt * 8 + (wave >> 1) * 4;
  const unsigned short* pa[4];
  const unsigned short* pb[4];
#pragma unroll
  for (int m = 0; m < 4; m++)
    pa[m] = a_f + ((size_t)(rt0 + m) * 64 + kp * 32) * 512 + lane * 8;
#pragma unroll
  for (int n = 0; n < 4; n++)
    pb[n] = w2f + ((size_t)(e * 64 + ntP0 + n) * 64 + kp * 32) * 512 + lane * 8;

  bf16x8 ac[4], bc[4];
#pragma unroll
  for (int m = 0; m < 4; m++) ac[m] = *reinterpret_cast<const bf16x8*>(pa[m]);
#pragma unroll
  for (int n = 0; n < 4; n++) bc[n] = *reinterpret_cast<const bf16x8*>(pb[n]);

  f32x4 acc[4][4] = {};
#pragma unroll 2
  for (int i = 0; i < 32; i++) {
    int o = (i < 31) ? (i + 1) * 512 : 0;   // prefetch next (guarded)
    bf16x8 an[4], bn[4];
#pragma unroll
    for (int m = 0; m < 4; m++) an[m] = *reinterpret_cast<const bf16x8*>(pa[m] + o);
#pragma unroll
    for (int n = 0; n < 4; n++) bn[n] = *reinterpret_cast<const bf16x8*>(pb[n] + o);
#pragma unroll
    for (int m = 0; m < 4; m++)
#pragma unroll
      for (int n = 0; n < 4; n++)
        acc[m][n] = __builtin_amdgcn_mfma_f32_16x16x32_bf16(ac[m], bc[n], acc[m][n], 0, 0, 0);
#pragma unroll
    for (int m = 0; m < 4; m++) ac[m] = an[m];
#pragma unroll
    for (int n = 0; n < 4; n++) bc[n] = bn[n];
  }
  unsigned short* yk = y + (size_t)kp * MAXROWS * HIDDEN;
#pragma unroll
  for (int m = 0; m < 4; m++)
#pragma unroll
    for (int n = 0; n < 4; n++) {
      int col = n0 + wc + n * 16 + ln;
#pragma unroll
      for (int r = 0; r < 4; r++) {
        int row = row0 + wr + m * 16 + quad * 4 + r;
        yk[(size_t)row * HIDDEN + col] = f2bf(acc[m][n][r]);
      }
    }
}

// ------- combine: out[t] = g0*(y0[s0]+y1[s0]) + g1*(y0[s1]+y1[s1]) ---------
__global__ __launch_bounds__(256) void k_combine(const unsigned short* __restrict__ y,
    const int* __restrict__ slots, const float* __restrict__ topkw,
    float* __restrict__ out) {
  int t = blockIdx.x;
  int c = threadIdx.x * 4;
  int s0 = slots[t * 2], s1 = slots[t * 2 + 1];
  float g0 = topkw[t * 2], g1 = topkw[t * 2 + 1];
  const unsigned short* y1 = y + (size_t)MAXROWS * HIDDEN;
  uint2 a0 = *reinterpret_cast<const uint2*>(y  + (size_t)s0 * HIDDEN + c);
  uint2 a1 = *reinterpret_cast<const uint2*>(y1 + (size_t)s0 * HIDDEN + c);
  uint2 b0 = *reinterpret_cast<const uint2*>(y  + (size_t)s1 * HIDDEN + c);
  uint2 b1 = *reinterpret_cast<const uint2*>(y1 + (size_t)s1 * HIDDEN + c);
  float4 o;
  o.x = g0 * (bf2f(a0.x & 0xffffu) + bf2f(a1.x & 0xffffu))
      + g1 * (bf2f(b0.x & 0xffffu) + bf2f(b1.x & 0xffffu));
  o.y = g0 * (bf2f(a0.x >> 16) + bf2f(a1.x >> 16))
      + g1 * (bf2f(b0.x >> 16) + bf2f(b1.x >> 16));
  o.z = g0 * (bf2f(a0.y & 0xffffu) + bf2f(a1.y & 0xffffu))
      + g1 * (bf2f(b0.y & 0xffffu) + bf2f(b1.y & 0xffffu));
  o.w = g0 * (bf2f(a0.y >> 16) + bf2f(a1.y >> 16))
      + g1 * (bf2f(b0.y >> 16) + bf2f(b1.y >> 16));
  *reinterpret_cast<float4*>(out + (size_t)t * HIDDEN + c) = o;
}

extern "C" void kernel_launch(void* const* d_in, const int* in_sizes, int n_in,
                              void* d_out, int out_size, void* d_ws, size_t ws_size,
                              hipStream_t stream) {
  const float* x   = (const float*)d_in[0];
  const float* rw  = (const float*)d_in[1];
  const int*   w1  = (const int*)d_in[2];
  const float* w1s = (const float*)d_in[3];
  const int*   w2  = (const int*)d_in[4];
  const float* w2s = (const float*)d_in[5];
  float* out = (float*)d_out;
  char* ws = (char*)d_ws;

  int*   topki = (int*)(ws + OFF_TOPKI);
  float* topkw = (float*)(ws + OFF_TOPKW);
  int*   ctrl  = (int*)(ws + OFF_CTRL);
  int*   tok   = (int*)(ws + OFF_TOK);
  int*   slots = (int*)(ws + OFF_SLOT);
  int*   tilemap = (int*)(ws + OFF_TILE);
  unsigned short* xb  = (unsigned short*)(ws + OFF_XB);
  unsigned short* a_f = (unsigned short*)(ws + OFF_A);
  unsigned short* w1d = (unsigned short*)(ws + OFF_W1D);
  unsigned short* w2f = (unsigned short*)(ws + OFF_W2D);
  unsigned short* y   = (unsigned short*)(ws + OFF_Y0);  // aliases dead w1d

  k_prep<<<25601, 256, 0, stream>>>(x, rw, topki, topkw, w1, w1s, w1d, w2, w2s, w2f, xb);
  k_route2<<<1, 256, 0, stream>>>(topki, ctrl, tok, slots, tilemap);
  k_gemm1<<<32 * MAXTILES, 256, 0, stream>>>(xb, w1d, ctrl, tilemap, tok, a_f);
  k_gemm2<<<16 * MAXTILES, 256, 0, stream>>>(a_f, w2f, ctrl, tilemap, y);
  k_combine<<<TOKENS, 256, 0, stream>>>(y, slots, topkw, out);
}